// Round 4
// baseline (61451.929 us; speedup 1.0000x reference)
//
#include <hip/hip_runtime.h>
#include <stdint.h>
#include <math.h>

// Persistent barrier-free 2-layer LSTM rollout, MI355X (gfx950).
// 512 WGs x 64 thr (1 wave); wave w owns h-units {2w, 2w+1}.
// ONE broadcast per step: every wave polls full h1(t), computes the
// Bernoulli sample s(t) redundantly (identical arithmetic -> identical
// result), and producers publish BOTH h0(t+1) outcomes (s=0/s=1) packed
// as {f16,f16,tag} per unit, concurrently with the h1 broadcast;
// consumers select with their local s. Parity double-buffered slots,
// parallel-sweep stale polling (no serialized confirmation loads).

#define H     1024
#define NSTEP 8192
#define NWG   512
#define BLK   64
#define NROW  25   // 0-7 Wih1, 8-15 Whh0, 16-23 Whh1, 24 W2

typedef _Float16 h2 __attribute__((ext_vector_type(2)));
typedef _Float16 h8 __attribute__((ext_vector_type(8)));
typedef unsigned long long u64;

union U32H2 { uint32_t u; h2 v; };

__device__ __forceinline__ u64 pack2(float v0, float v1, uint32_t tag){
  U32H2 p; p.v.x = (_Float16)v0; p.v.y = (_Float16)v1;
  return ((u64)tag << 32) | (u64)p.u;
}

// Exact JAX threefry2x32.
__device__ __forceinline__ uint2 tf2x32(uint32_t k0, uint32_t k1, uint32_t x0, uint32_t x1){
  uint32_t k2 = k0 ^ k1 ^ 0x1BD11BDAu;
  x0 += k0; x1 += k1;
#define TFR(r) { x0 += x1; x1 = (x1 << (r)) | (x1 >> (32 - (r))); x1 ^= x0; }
  TFR(13) TFR(15) TFR(26) TFR(6)
  x0 += k1; x1 += k2 + 1u;
  TFR(17) TFR(29) TFR(16) TFR(24)
  x0 += k2; x1 += k0 + 2u;
  TFR(13) TFR(15) TFR(26) TFR(6)
  x0 += k0; x1 += k1 + 3u;
  TFR(17) TFR(29) TFR(16) TFR(24)
  x0 += k1; x1 += k2 + 4u;
  TFR(13) TFR(15) TFR(26) TFR(6)
  x0 += k2; x1 += k0 + 5u;
#undef TFR
  uint2 r; r.x = x0; r.y = x1; return r;
}

// keys = threefry_split(key(42), 8192)
__device__ __forceinline__ uint32_t jax_word(uint32_t i){
  return (i < 8192u) ? tf2x32(0u, 42u, i, i + 8192u).x
                     : tf2x32(0u, 42u, i - 8192u, i).y;
}

__device__ __forceinline__ float wred64(float x){
  #pragma unroll
  for(int off = 32; off > 0; off >>= 1) x += __shfl_xor(x, off, 64);
  return x;
}

#if __has_builtin(__builtin_amdgcn_fdot2)
__device__ __forceinline__ float fdot2f(h2 a, h2 b, float c){ return __builtin_amdgcn_fdot2(a, b, c, false); }
#else
__device__ __forceinline__ float fdot2f(h2 a, h2 b, float c){
  return (float)a.x * (float)b.x + (float)a.y * (float)b.y + c;
}
#endif

__device__ __forceinline__ float sigm(float x){
  x = fminf(fmaxf(x, -30.f), 30.f);
  return 1.f / (1.f + __expf(-x));
}
__device__ __forceinline__ float tanh_f(float x){
  x = fminf(fmaxf(x, -15.f), 15.f);
  float e = __expf(2.f * x);
  return (e - 1.f) / (e + 1.f);
}

__device__ __forceinline__ u64 ld_slot(const u64* p){
  return __hip_atomic_load((u64*)p, __ATOMIC_RELAXED, __HIP_MEMORY_SCOPE_AGENT);
}
__device__ __forceinline__ void st_slot(u64* p, u64 v){
  __hip_atomic_store(p, v, __ATOMIC_RELAXED, __HIP_MEMORY_SCOPE_AGENT);
}

__device__ __forceinline__ void issue4(const u64* p, u64* pv){
  #pragma unroll
  for(int k = 0; k < 4; k++) pv[k] = ld_slot(p + k);
}
__device__ __forceinline__ void issue8(const u64* p, u64* pv){
  #pragma unroll
  for(int k = 0; k < 8; k++) pv[k] = ld_slot(p + k);
}

// Parallel-sweep wait: re-issue ALL stale slots each sweep (loads pipeline),
// re-check. No serialized per-slot confirmation chains.
__device__ __forceinline__ void wait8(const u64* p0, const u64* p1, uint32_t tag, u64* pv){
  for(;;){
    uint32_t bad = 0;
    #pragma unroll
    for(int k = 0; k < 8; k++) bad |= ((uint32_t)(pv[k] >> 32)) ^ tag;
    if(!bad) break;
    __builtin_amdgcn_s_sleep(1);
    #pragma unroll
    for(int k = 0; k < 4; k++) if(((uint32_t)(pv[k] >> 32)) != tag)     pv[k]     = ld_slot(p0 + k);
    #pragma unroll
    for(int k = 0; k < 4; k++) if(((uint32_t)(pv[4+k] >> 32)) != tag)   pv[4+k]   = ld_slot(p1 + k);
  }
}
__device__ __forceinline__ void wait16(const u64* q0, const u64* q1, uint32_t tag, u64* cv){
  for(;;){
    uint32_t bad = 0;
    #pragma unroll
    for(int k = 0; k < 16; k++) bad |= ((uint32_t)(cv[k] >> 32)) ^ tag;
    if(!bad) break;
    __builtin_amdgcn_s_sleep(1);
    #pragma unroll
    for(int k = 0; k < 8; k++) if(((uint32_t)(cv[k] >> 32)) != tag)     cv[k]     = ld_slot(q0 + k);
    #pragma unroll
    for(int k = 0; k < 8; k++) if(((uint32_t)(cv[8+k] >> 32)) != tag)   cv[8+k]   = ld_slot(q1 + k);
  }
}

__device__ __forceinline__ void unpack8(const u64* pv, h2* hv){
  #pragma unroll
  for(int k = 0; k < 8; k++){ U32H2 p; p.u = (uint32_t)pv[k]; hv[k] = p.v; }
}

// Select h0 fragment from candidate slots: sh = 0 (s=0, low16) or 16 (s=1).
__device__ __forceinline__ void sel_h0(const u64* cv, uint32_t sh, h2* hv){
  #pragma unroll
  for(int m = 0; m < 8; m++){
    uint32_t lo = (((uint32_t)cv[2*m])     >> sh) & 0xffffu;
    uint32_t hi = (((uint32_t)cv[2*m + 1]) >> sh) & 0xffffu;
    U32H2 p; p.u = lo | (hi << 16); hv[m] = p.v;
  }
}

// Row dot partial: lane l covers h2 [4l,4l+4) and [256+4l,+4): two b128
// LDS reads, lane stride 16B -> conflict-free.
__device__ __forceinline__ float row_part(const h2* __restrict__ wrow, int lane, const h2* hv){
  h8 wl = *(const h8*)(wrow + (lane << 2));
  h8 wh = *(const h8*)(wrow + 256 + (lane << 2));
  float a0 = 0.f, a1 = 0.f;
  h2 w;
  w = __builtin_shufflevector(wl, wl, 0, 1); a0 = fdot2f(w, hv[0], a0);
  w = __builtin_shufflevector(wl, wl, 2, 3); a1 = fdot2f(w, hv[1], a1);
  w = __builtin_shufflevector(wl, wl, 4, 5); a0 = fdot2f(w, hv[2], a0);
  w = __builtin_shufflevector(wl, wl, 6, 7); a1 = fdot2f(w, hv[3], a1);
  w = __builtin_shufflevector(wh, wh, 0, 1); a0 = fdot2f(w, hv[4], a0);
  w = __builtin_shufflevector(wh, wh, 2, 3); a1 = fdot2f(w, hv[5], a1);
  w = __builtin_shufflevector(wh, wh, 4, 5); a0 = fdot2f(w, hv[6], a0);
  w = __builtin_shufflevector(wh, wh, 6, 7); a1 = fdot2f(w, hv[7], a1);
  return a0 + a1;
}

__global__ void __launch_bounds__(BLK)
lstm_persist(const float* __restrict__ ctx,  const float* __restrict__ W1p,  const float* __restrict__ b1p,
             const float* __restrict__ Wih0, const float* __restrict__ Whh0,
             const float* __restrict__ bih0, const float* __restrict__ bhh0,
             const float* __restrict__ Wih1, const float* __restrict__ Whh1,
             const float* __restrict__ bih1, const float* __restrict__ bhh1,
             const float* __restrict__ W2p,  const float* __restrict__ b2p,
             float* __restrict__ out,
             u64* __restrict__ h1b,   // [2][512] parity-double-buffered h1 slots
             u64* __restrict__ cb)    // [2][1024] parity-double-buffered h0 candidate slots
{
  __shared__ h2 w[NROW][H/2];   // 51.2 KB; 512 WGs -> 2/CU co-resident

  const int lane = threadIdx.x;
  const int wg   = blockIdx.x;
  const int j0   = wg << 1;

  // ---- one-time: stage 25 rows as f16 (coalesced float4 reads)
  #pragma unroll 1
  for(int r = 0; r < NROW; r++){
    const float* rowp;
    if(r < 8)      { int g = r & 3,  j = j0 + (r >> 2);               rowp = Wih1 + (size_t)(g*H + j)*H; }
    else if(r < 16){ int rr = r - 8;  int g = rr & 3, j = j0 + (rr >> 2); rowp = Whh0 + (size_t)(g*H + j)*H; }
    else if(r < 24){ int rr = r - 16; int g = rr & 3, j = j0 + (rr >> 2); rowp = Whh1 + (size_t)(g*H + j)*H; }
    else           rowp = W2p;
    const float4* s4 = (const float4*)rowp;
    #pragma unroll
    for(int it = 0; it < 4; it++){
      float4 f = s4[lane + (it << 6)];
      h2 pa; pa.x = (_Float16)f.x; pa.y = (_Float16)f.y;
      h2 pb; pb.x = (_Float16)f.z; pb.y = (_Float16)f.w;
      const int ci = (lane + (it << 6)) << 1;
      w[r][ci] = pa; w[r][ci + 1] = pb;
    }
  }
  __syncthreads();

  // per-wave scalars (uniform)
  float b0g[8], b1g[8], w0g[8];
  #pragma unroll
  for(int e = 0; e < 2; e++){
    const int j = j0 + e;
    #pragma unroll
    for(int g = 0; g < 4; g++){
      b0g[4*e + g] = bih0[g*H + j] + bhh0[g*H + j];
      b1g[4*e + g] = bih1[g*H + j] + bhh1[g*H + j];
      w0g[4*e + g] = Wih0[g*H + j];
    }
  }
  const float b2v = b2p[0];

  // x0 = W1 @ context + b1
  float xacc = 0.f;
  for(int c = lane; c < 512; c += 64) xacc += W1p[c] * ctx[c];
  const float x0 = wred64(xacc) + b1p[0];

  float c0v[2], c1v[2] = {0.f, 0.f}, logp = 0.f;
  float a1[8] = {0.f,0.f,0.f,0.f,0.f,0.f,0.f,0.f};
  float ubatch = 0.f;

  // ---- bootstrap: h0(0) for own units; publish as identical candidates, tag 0, cb[0]
  {
    float h00[2];
    #pragma unroll
    for(int e = 0; e < 2; e++){
      float gi = sigm (w0g[4*e+0]*x0 + b0g[4*e+0]);
      float gf = sigm (w0g[4*e+1]*x0 + b0g[4*e+1]);  (void)gf;
      float gg = tanh_f(w0g[4*e+2]*x0 + b0g[4*e+2]);
      float go = sigm (w0g[4*e+3]*x0 + b0g[4*e+3]);
      c0v[e] = gi * gg;
      h00[e] = go * tanh_f(c0v[e]);
    }
    if(lane == 0){
      st_slot(&cb[j0],     pack2(h00[0], h00[0], 0u));
      st_slot(&cb[j0 + 1], pack2(h00[1], h00[1], 0u));
    }
  }

  h2 hv0[8], hv1[8];
  // pre-loop: poll cand tag 0 (identical copies; select s=0)
  {
    const u64* q0 = cb + (lane << 3);
    const u64* q1 = cb + 512 + (lane << 3);
    u64 cv[16];
    issue8(q0, cv); issue8(q1, cv + 8);
    wait16(q0, q1, 0u, cv);
    sel_h0(cv, 0u, hv0);
  }

  #pragma unroll 1
  for(int t = 0; t < NSTEP; t++){
    const uint32_t tt = (uint32_t)t;
    u64* hb  = h1b + ((t & 1) << 9);          // h1(t) slots, tag tt
    u64* cbn = cb  + (((t + 1) & 1) << 10);   // h0(t+1) candidate slots, tag tt+1

    // ---- step 1: layer-1 gates on hv0 -> publish h1(t)
    float s1[8];
    #pragma unroll
    for(int r = 0; r < 8; r++) s1[r] = row_part(&w[r][0], lane, hv0);
    #pragma unroll
    for(int off = 32; off > 0; off >>= 1){
      #pragma unroll
      for(int r = 0; r < 8; r++) s1[r] += __shfl_xor(s1[r], off, 64);
    }
    {
      float h1v[2];
      #pragma unroll
      for(int e = 0; e < 2; e++){
        float gi = sigm (s1[4*e+0] + a1[4*e+0] + b1g[4*e+0]);
        float gf = sigm (s1[4*e+1] + a1[4*e+1] + b1g[4*e+1]);
        float gg = tanh_f(s1[4*e+2] + a1[4*e+2] + b1g[4*e+2]);
        float go = sigm (s1[4*e+3] + a1[4*e+3] + b1g[4*e+3]);
        c1v[e] = gf*c1v[e] + gi*gg;
        h1v[e] = go * tanh_f(c1v[e]);
      }
      if(lane == 0)
        st_slot(&hb[wg], pack2(h1v[0], h1v[1], tt));
    }

    // ---- step 1.5: issue h1 poll first sweep (overlaps shadow below)
    const u64* hp0 = hb + (lane << 2);
    const u64* hp1 = hb + 256 + (lane << 2);
    u64 pv[8];
    issue4(hp0, pv); issue4(hp1, pv + 4);

    // ---- step 2 (shadow): a0 = Whh0 @ h0(t)
    float a0[8];
    #pragma unroll
    for(int r = 0; r < 8; r++) a0[r] = row_part(&w[8 + r][0], lane, hv0);
    #pragma unroll
    for(int off = 32; off > 0; off >>= 1){
      #pragma unroll
      for(int r = 0; r < 8; r++) a0[r] += __shfl_xor(a0[r], off, 64);
    }

    // ---- step 3 (shadow): both h0(t+1) candidates -> publish (tag tt+1)
    float c0c[2][2];
    {
      float h0c[2][2];
      #pragma unroll
      for(int e = 0; e < 2; e++){
        #pragma unroll
        for(int sb = 0; sb < 2; sb++){
          const float sv = (float)sb;
          float gi = sigm (a0[4*e+0] + w0g[4*e+0]*sv + b0g[4*e+0]);
          float gf = sigm (a0[4*e+1] + w0g[4*e+1]*sv + b0g[4*e+1]);
          float gg = tanh_f(a0[4*e+2] + w0g[4*e+2]*sv + b0g[4*e+2]);
          float go = sigm (a0[4*e+3] + w0g[4*e+3]*sv + b0g[4*e+3]);
          float cc = gf*c0v[e] + gi*gg;
          c0c[e][sb] = cc;
          h0c[e][sb] = go * tanh_f(cc);
        }
      }
      if(lane == 0){
        st_slot(&cbn[j0],     pack2(h0c[0][0], h0c[0][1], tt + 1u));
        st_slot(&cbn[j0 + 1], pack2(h0c[1][0], h0c[1][1], tt + 1u));
      }
    }

    // ---- step 4 (shadow): batched RNG refill (64 steps per burst)
    if((t & 63) == 0){
      const uint32_t i0 = (uint32_t)t + (uint32_t)lane;
      const uint32_t kk0 = jax_word(2u*i0), kk1 = jax_word(2u*i0 + 1u);
      const uint32_t bits = tf2x32(kk0, kk1, 0u, 0u).x;
      ubatch = __uint_as_float((bits >> 9) | 0x3f800000u) - 1.0f;
    }

    // ---- step 5: finish h1 poll
    wait8(hp0, hp1, tt, pv);
    unpack8(pv, hv1);

    // ---- step 6a: issue candidate poll first sweep
    const u64* cq0 = cbn + (lane << 3);
    const u64* cq1 = cbn + 512 + (lane << 3);
    u64 cv[16];
    if(t < NSTEP - 1){ issue8(cq0, cv); issue8(cq1, cv + 8); }

    // ---- step 6b: redundant sample s(t)
    float z = row_part(&w[24][0], lane, hv1);
    z = wred64(z) + b2v;
    const float p = sigm(z);
    const float u = __shfl(ubatch, t & 63, 64);
    const bool  sb_ = (u < p);
    const float s = sb_ ? 1.f : 0.f;
    logp += sb_ ? __logf(p) : __logf(1.f - p);
    if(wg == 0 && lane == 0) out[t] = s;
    c0v[0] = sb_ ? c0c[0][1] : c0c[0][0];
    c0v[1] = sb_ ? c0c[1][1] : c0c[1][0];

    // ---- step 6c (shadow of candidate flight): a1 = Whh1 @ h1(t)
    #pragma unroll
    for(int r = 0; r < 8; r++) a1[r] = row_part(&w[16 + r][0], lane, hv1);
    #pragma unroll
    for(int off = 32; off > 0; off >>= 1){
      #pragma unroll
      for(int r = 0; r < 8; r++) a1[r] += __shfl_xor(a1[r], off, 64);
    }

    // ---- step 7: finish candidate poll, select h0(t+1) with s(t)
    if(t < NSTEP - 1){
      wait16(cq0, cq1, tt + 1u, cv);
      sel_h0(cv, sb_ ? 16u : 0u, hv0);
    }
  }

  if(wg == 0 && lane == 0) out[NSTEP] = logp;
}

extern "C" void kernel_launch(void* const* d_in, const int* in_sizes, int n_in,
                              void* d_out, int out_size, void* d_ws, size_t ws_size,
                              hipStream_t stream){
  u64* h1b = (u64*)d_ws;          // [2][512]
  u64* cb  = h1b + 1024;          // [2][1024]  (total 24 KB of d_ws)
  hipLaunchKernelGGL(lstm_persist, dim3(NWG), dim3(BLK), 0, stream,
    (const float*)d_in[0],  (const float*)d_in[1],  (const float*)d_in[2],
    (const float*)d_in[3],  (const float*)d_in[4],  (const float*)d_in[5],  (const float*)d_in[6],
    (const float*)d_in[7],  (const float*)d_in[8],  (const float*)d_in[9],  (const float*)d_in[10],
    (const float*)d_in[11], (const float*)d_in[12],
    (float*)d_out, h1b, cb);
}

// Round 5
// 36667.050 us; speedup vs baseline: 1.6759x; 1.6759x over previous
//
#include <hip/hip_runtime.h>
#include <stdint.h>
#include <math.h>

// Persistent barrier-free 2-layer LSTM rollout, MI355X (gfx950).
// R3 skeleton (proven): 512 WGs x 64 thr; wave w owns h-units {2w,2w+1}.
// Two broadcast phases/step via 8B {2xf16 | u32 tag} relaxed agent atomics.
// R5 changes: merge-tree scatter reduction (10 shfl vs 48), local candidate
// precompute for h0(t+1) (P2 chain = W2 row + select only), batched threefry,
// 8x-replicated broadcast buffers (consumer polls replica wg&7).

#define H     1024
#define NSTEP 8192
#define NWG   512
#define BLK   64
#define NROW  25   // 0-7 Wih1, 8-15 Whh0, 16-23 Whh1, 24 W2

typedef _Float16 h2 __attribute__((ext_vector_type(2)));
typedef _Float16 h8 __attribute__((ext_vector_type(8)));
typedef unsigned long long u64;

union U32H2 { uint32_t u; h2 v; };

__device__ __forceinline__ u64 pack2(float v0, float v1, uint32_t tag){
  U32H2 p; p.v.x = (_Float16)v0; p.v.y = (_Float16)v1;
  return ((u64)tag << 32) | (u64)p.u;
}

// Exact JAX threefry2x32.
__device__ __forceinline__ uint2 tf2x32(uint32_t k0, uint32_t k1, uint32_t x0, uint32_t x1){
  uint32_t k2 = k0 ^ k1 ^ 0x1BD11BDAu;
  x0 += k0; x1 += k1;
#define TFR(r) { x0 += x1; x1 = (x1 << (r)) | (x1 >> (32 - (r))); x1 ^= x0; }
  TFR(13) TFR(15) TFR(26) TFR(6)
  x0 += k1; x1 += k2 + 1u;
  TFR(17) TFR(29) TFR(16) TFR(24)
  x0 += k2; x1 += k0 + 2u;
  TFR(13) TFR(15) TFR(26) TFR(6)
  x0 += k0; x1 += k1 + 3u;
  TFR(17) TFR(29) TFR(16) TFR(24)
  x0 += k1; x1 += k2 + 4u;
  TFR(13) TFR(15) TFR(26) TFR(6)
  x0 += k2; x1 += k0 + 5u;
#undef TFR
  uint2 r; r.x = x0; r.y = x1; return r;
}

// keys = threefry_split(key(42), 8192)
__device__ __forceinline__ uint32_t jax_word(uint32_t i){
  return (i < 8192u) ? tf2x32(0u, 42u, i, i + 8192u).x
                     : tf2x32(0u, 42u, i - 8192u, i).y;
}

__device__ __forceinline__ float wred64(float x){
  #pragma unroll
  for(int off = 32; off > 0; off >>= 1) x += __shfl_xor(x, off, 64);
  return x;
}

// Merge-tree reduce of 8 per-lane partials over 64 lanes.
// After 6 levels lane l holds total of row (l&7); broadcast via readlane.
// 10 shuffles + 8 readlanes vs 48 shuffles for the naive butterfly.
__device__ __forceinline__ void mreduce8(int lane, const float* v, float* s){
  const bool b1 = lane & 1;
  float t, w0, w1, w2, w3;
  t = b1 ? v[0] : v[1]; w0 = (b1 ? v[1] : v[0]) + __shfl_xor(t, 1, 64);
  t = b1 ? v[2] : v[3]; w1 = (b1 ? v[3] : v[2]) + __shfl_xor(t, 1, 64);
  t = b1 ? v[4] : v[5]; w2 = (b1 ? v[5] : v[4]) + __shfl_xor(t, 1, 64);
  t = b1 ? v[6] : v[7]; w3 = (b1 ? v[7] : v[6]) + __shfl_xor(t, 1, 64);
  const bool b2 = lane & 2;
  float u0, u1;
  t = b2 ? w0 : w1; u0 = (b2 ? w1 : w0) + __shfl_xor(t, 2, 64);
  t = b2 ? w2 : w3; u1 = (b2 ? w3 : w2) + __shfl_xor(t, 2, 64);
  const bool b4 = lane & 4;
  t = b4 ? u0 : u1; float z = (b4 ? u1 : u0) + __shfl_xor(t, 4, 64);
  z += __shfl_xor(z, 8, 64);
  z += __shfl_xor(z, 16, 64);
  z += __shfl_xor(z, 32, 64);
  #pragma unroll
  for(int r = 0; r < 8; r++) s[r] = __shfl(z, r, 64);
}

#if __has_builtin(__builtin_amdgcn_fdot2)
__device__ __forceinline__ float fdot2f(h2 a, h2 b, float c){ return __builtin_amdgcn_fdot2(a, b, c, false); }
#else
__device__ __forceinline__ float fdot2f(h2 a, h2 b, float c){
  return (float)a.x * (float)b.x + (float)a.y * (float)b.y + c;
}
#endif

__device__ __forceinline__ float sigm(float x){
  x = fminf(fmaxf(x, -30.f), 30.f);
  return 1.f / (1.f + __expf(-x));
}
__device__ __forceinline__ float tanh_f(float x){
  x = fminf(fmaxf(x, -15.f), 15.f);
  float e = __expf(2.f * x);
  return (e - 1.f) / (e + 1.f);
}

__device__ __forceinline__ u64 ld_slot(const u64* p){
  return __hip_atomic_load((u64*)p, __ATOMIC_RELAXED, __HIP_MEMORY_SCOPE_AGENT);
}
__device__ __forceinline__ void st_slot(u64* p, u64 v){
  __hip_atomic_store(p, v, __ATOMIC_RELAXED, __HIP_MEMORY_SCOPE_AGENT);
}

// Poll this lane's 8 slots from the given replica; parallel re-sweep of
// stale slots only. Called AFTER shadow compute (data usually ready).
__device__ __forceinline__ void poll_h(const u64* __restrict__ buf,
                                       uint32_t tag, int lane, h2* hv){
  const u64* p0 = buf + (lane << 2);
  const u64* p1 = buf + 256 + (lane << 2);
  u64 pv[8];
  #pragma unroll
  for(int k = 0; k < 4; k++) pv[k]     = ld_slot(p0 + k);
  #pragma unroll
  for(int k = 0; k < 4; k++) pv[4 + k] = ld_slot(p1 + k);
  for(;;){
    uint32_t bad = 0;
    #pragma unroll
    for(int k = 0; k < 8; k++) bad |= ((uint32_t)(pv[k] >> 32)) ^ tag;
    if(!bad) break;
    __builtin_amdgcn_s_sleep(1);
    #pragma unroll
    for(int k = 0; k < 4; k++) if(((uint32_t)(pv[k] >> 32)) != tag)   pv[k]     = ld_slot(p0 + k);
    #pragma unroll
    for(int k = 0; k < 4; k++) if(((uint32_t)(pv[4+k] >> 32)) != tag) pv[4+k]   = ld_slot(p1 + k);
  }
  #pragma unroll
  for(int k = 0; k < 8; k++){ U32H2 p; p.u = (uint32_t)pv[k]; hv[k] = p.v; }
}

// Publish pk (uniform across lanes) to all 8 replicas: lanes 0-7, one store.
__device__ __forceinline__ void publish(u64* __restrict__ rep, int wg, int lane, u64 pk){
  if(lane < 8) st_slot(rep + (lane << 9) + wg, pk);
}

// Row dot partial: lane l covers h2 [4l,4l+4) and [256+4l,+4): two b128
// LDS reads, lane stride 16B.
__device__ __forceinline__ float row_part(const h2* __restrict__ wrow, int lane, const h2* hv){
  h8 wl = *(const h8*)(wrow + (lane << 2));
  h8 wh = *(const h8*)(wrow + 256 + (lane << 2));
  float a0 = 0.f, a1 = 0.f;
  h2 w;
  w = __builtin_shufflevector(wl, wl, 0, 1); a0 = fdot2f(w, hv[0], a0);
  w = __builtin_shufflevector(wl, wl, 2, 3); a1 = fdot2f(w, hv[1], a1);
  w = __builtin_shufflevector(wl, wl, 4, 5); a0 = fdot2f(w, hv[2], a0);
  w = __builtin_shufflevector(wl, wl, 6, 7); a1 = fdot2f(w, hv[3], a1);
  w = __builtin_shufflevector(wh, wh, 0, 1); a0 = fdot2f(w, hv[4], a0);
  w = __builtin_shufflevector(wh, wh, 2, 3); a1 = fdot2f(w, hv[5], a1);
  w = __builtin_shufflevector(wh, wh, 4, 5); a0 = fdot2f(w, hv[6], a0);
  w = __builtin_shufflevector(wh, wh, 6, 7); a1 = fdot2f(w, hv[7], a1);
  return a0 + a1;
}

__global__ void __launch_bounds__(BLK)
lstm_persist(const float* __restrict__ ctx,  const float* __restrict__ W1p,  const float* __restrict__ b1p,
             const float* __restrict__ Wih0, const float* __restrict__ Whh0,
             const float* __restrict__ bih0, const float* __restrict__ bhh0,
             const float* __restrict__ Wih1, const float* __restrict__ Whh1,
             const float* __restrict__ bih1, const float* __restrict__ bhh1,
             const float* __restrict__ W2p,  const float* __restrict__ b2p,
             float* __restrict__ out,
             u64* __restrict__ h0rep,   // [8][512] replicated h0 slots
             u64* __restrict__ h1rep)   // [8][512] replicated h1 slots
{
  __shared__ h2 w[NROW][H/2];   // 51.2 KB; 2 WGs/CU co-resident

  const int lane = threadIdx.x;
  const int wg   = blockIdx.x;
  const int j0   = wg << 1;
  const u64* myh0 = h0rep + ((size_t)(wg & 7) << 9);
  const u64* myh1 = h1rep + ((size_t)(wg & 7) << 9);

  // ---- one-time: stage 25 rows as f16 (coalesced float4 reads)
  #pragma unroll 1
  for(int r = 0; r < NROW; r++){
    const float* rowp;
    if(r < 8)      { int g = r & 3,  j = j0 + (r >> 2);                   rowp = Wih1 + (size_t)(g*H + j)*H; }
    else if(r < 16){ int rr = r - 8;  int g = rr & 3, j = j0 + (rr >> 2); rowp = Whh0 + (size_t)(g*H + j)*H; }
    else if(r < 24){ int rr = r - 16; int g = rr & 3, j = j0 + (rr >> 2); rowp = Whh1 + (size_t)(g*H + j)*H; }
    else           rowp = W2p;
    const float4* s4 = (const float4*)rowp;
    #pragma unroll
    for(int it = 0; it < 4; it++){
      float4 f = s4[lane + (it << 6)];
      h2 pa; pa.x = (_Float16)f.x; pa.y = (_Float16)f.y;
      h2 pb; pb.x = (_Float16)f.z; pb.y = (_Float16)f.w;
      const int ci = (lane + (it << 6)) << 1;
      w[r][ci] = pa; w[r][ci + 1] = pb;
    }
  }
  __syncthreads();

  // per-wave scalars (uniform)
  float b0g[8], b1g[8], w0g[8];
  #pragma unroll
  for(int e = 0; e < 2; e++){
    const int j = j0 + e;
    #pragma unroll
    for(int g = 0; g < 4; g++){
      b0g[4*e + g] = bih0[g*H + j] + bhh0[g*H + j];
      b1g[4*e + g] = bih1[g*H + j] + bhh1[g*H + j];
      w0g[4*e + g] = Wih0[g*H + j];
    }
  }
  const float b2v = b2p[0];

  // x0 = W1 @ context + b1
  float xacc = 0.f;
  for(int c = lane; c < 512; c += 64) xacc += W1p[c] * ctx[c];
  const float x0 = wred64(xacc) + b1p[0];

  float c0v[2], c1v[2] = {0.f, 0.f}, logp = 0.f;
  float a1[8] = {0.f,0.f,0.f,0.f,0.f,0.f,0.f,0.f};
  float ubatch = 0.f;

  // h0(0) from x0, publish tag 1 to all replicas
  {
    float h00[2];
    #pragma unroll
    for(int e = 0; e < 2; e++){
      float gi = sigm (w0g[4*e+0]*x0 + b0g[4*e+0]);
      float gg = tanh_f(w0g[4*e+2]*x0 + b0g[4*e+2]);
      float go = sigm (w0g[4*e+3]*x0 + b0g[4*e+3]);
      c0v[e] = gi * gg;
      h00[e] = go * tanh_f(c0v[e]);
    }
    publish(h0rep, wg, lane, pack2(h00[0], h00[1], 1u));
  }

  h2 hv[8];

  #pragma unroll 1
  for(int t = 0; t < NSTEP; t++){
    const uint32_t tt = (uint32_t)t;

    // ================= P1: consume h0(t) =================
    poll_h(myh0, tt + 1u, lane, hv);

    // critical: 8 layer-1 gate rows -> merge-reduce -> cell1 -> publish h1(t)
    float pr[8], s1[8];
    #pragma unroll
    for(int r = 0; r < 8; r++) pr[r] = row_part(&w[r][0], lane, hv);
    mreduce8(lane, pr, s1);
    {
      float h1v[2];
      #pragma unroll
      for(int e = 0; e < 2; e++){
        float gi = sigm (s1[4*e+0] + a1[4*e+0] + b1g[4*e+0]);
        float gf = sigm (s1[4*e+1] + a1[4*e+1] + b1g[4*e+1]);
        float gg = tanh_f(s1[4*e+2] + a1[4*e+2] + b1g[4*e+2]);
        float go = sigm (s1[4*e+3] + a1[4*e+3] + b1g[4*e+3]);
        c1v[e] = gf*c1v[e] + gi*gg;
        h1v[e] = go * tanh_f(c1v[e]);
      }
      publish(h1rep, wg, lane, pack2(h1v[0], h1v[1], tt + 1u));
    }

    // ---- shadow1: RNG refill (1/64 steps), a0 rows, local h0(t+1) candidates
    if((t & 63) == 0){
      const uint32_t i0 = (uint32_t)t + (uint32_t)lane;
      const uint32_t kk0 = jax_word(2u*i0), kk1 = jax_word(2u*i0 + 1u);
      const uint32_t bits = tf2x32(kk0, kk1, 0u, 0u).x;
      ubatch = __uint_as_float((bits >> 9) | 0x3f800000u) - 1.0f;
    }
    float a0p[8], a0[8];
    #pragma unroll
    for(int r = 0; r < 8; r++) a0p[r] = row_part(&w[8 + r][0], lane, hv);
    mreduce8(lane, a0p, a0);

    float c0c[2][2], h0c[2][2];   // both s-outcomes, locally (uniform)
    #pragma unroll
    for(int e = 0; e < 2; e++){
      #pragma unroll
      for(int sb = 0; sb < 2; sb++){
        const float sv = (float)sb;
        float gi = sigm (a0[4*e+0] + w0g[4*e+0]*sv + b0g[4*e+0]);
        float gf = sigm (a0[4*e+1] + w0g[4*e+1]*sv + b0g[4*e+1]);
        float gg = tanh_f(a0[4*e+2] + w0g[4*e+2]*sv + b0g[4*e+2]);
        float go = sigm (a0[4*e+3] + w0g[4*e+3]*sv + b0g[4*e+3]);
        float cc = gf*c0v[e] + gi*gg;
        c0c[e][sb] = cc;
        h0c[e][sb] = go * tanh_f(cc);
      }
    }

    // ================= P2: consume h1(t) =================
    poll_h(myh1, tt + 1u, lane, hv);

    // critical: W2 row -> wred -> s -> select -> publish h0(t+1)
    float z = row_part(&w[24][0], lane, hv);
    z = wred64(z) + b2v;
    const float p = sigm(z);
    const float u = __shfl(ubatch, t & 63, 64);
    const bool  sb_ = (u < p);
    c0v[0] = sb_ ? c0c[0][1] : c0c[0][0];
    c0v[1] = sb_ ? c0c[1][1] : c0c[1][0];
    publish(h0rep, wg, lane,
            pack2(sb_ ? h0c[0][1] : h0c[0][0], sb_ ? h0c[1][1] : h0c[1][0], tt + 2u));

    logp += sb_ ? __logf(p) : __logf(1.f - p);
    if(wg == 0 && lane == 0) out[t] = sb_ ? 1.f : 0.f;

    // ---- shadow2: a1 = Whh1 @ h1(t)
    float a1p[8];
    #pragma unroll
    for(int r = 0; r < 8; r++) a1p[r] = row_part(&w[16 + r][0], lane, hv);
    mreduce8(lane, a1p, a1);
  }

  if(wg == 0 && lane == 0) out[NSTEP] = logp;
}

extern "C" void kernel_launch(void* const* d_in, const int* in_sizes, int n_in,
                              void* d_out, int out_size, void* d_ws, size_t ws_size,
                              hipStream_t stream){
  u64* h0rep = (u64*)d_ws;          // [8][512]
  u64* h1rep = h0rep + 8 * 512;     // [8][512]   (64 KB of d_ws total)
  hipLaunchKernelGGL(lstm_persist, dim3(NWG), dim3(BLK), 0, stream,
    (const float*)d_in[0],  (const float*)d_in[1],  (const float*)d_in[2],
    (const float*)d_in[3],  (const float*)d_in[4],  (const float*)d_in[5],  (const float*)d_in[6],
    (const float*)d_in[7],  (const float*)d_in[8],  (const float*)d_in[9],  (const float*)d_in[10],
    (const float*)d_in[11], (const float*)d_in[12],
    (float*)d_out, h0rep, h1rep);
}